// Round 4
// baseline (607.280 us; speedup 1.0000x reference)
//
#include <hip/hip_runtime.h>
#include <cstddef>

#define NN 100000
#define EE 1600000
#define F_IN 128
#define HID 48
#define NCLS 40
#define EPSV 1e-5f
#define SLOPE 0.01f
#define FIXP 16777216.0f   // 2^24 fixed-point scale for edge weights
#define AGG_BLOCKS 2048

typedef _Float16 half4 __attribute__((ext_vector_type(4)));
typedef _Float16 half8 __attribute__((ext_vector_type(8)));

__device__ inline void fma4(float4& a, float s, const float4 w) {
    a.x += s * w.x; a.y += s * w.y; a.z += s * w.z; a.w += s * w.w;
}

// ---------- edge preprocessing ----------

// ONE u64 atomic per edge: high32 = count, low32 = fixed-point weight sum.
// Returned old count = this edge's rank within its destination row.
__global__ void k_edge_deg(const int* __restrict__ ei, const float* __restrict__ ew,
                           unsigned long long* __restrict__ packed, int* __restrict__ rank) {
    int e = blockIdx.x * 256 + threadIdx.x;
    if (e < EE) {
        int d = ei[EE + e];
        unsigned long long add = (1ULL << 32) | (unsigned long long)__float2uint_rn(ew[e] * FIXP);
        unsigned long long old = atomicAdd(&packed[d], add);
        rank[e] = (int)(old >> 32);
    }
}

// scan part 1 + dinv computation (packed already in hand)
__global__ void k_scan1(const unsigned long long* __restrict__ packed, int* __restrict__ row_start,
                        int* __restrict__ partials, float* __restrict__ dinv) {
    __shared__ int tmp[1024];
    int tid = threadIdx.x;
    int i = blockIdx.x * 1024 + tid;
    unsigned long long p = (i < NN) ? packed[i] : 0ULL;
    int v = (int)(p >> 32);
    if (i < NN) {
        float wdeg = (float)(unsigned int)(p & 0xffffffffULL) * (1.0f / FIXP);
        dinv[i] = rsqrtf(wdeg + 1.0f);   // +1 = self-loop weight; always > 0
    }
    tmp[tid] = v;
    __syncthreads();
    for (int off = 1; off < 1024; off <<= 1) {
        int t = (tid >= off) ? tmp[tid - off] : 0;
        __syncthreads();
        tmp[tid] += t;
        __syncthreads();
    }
    if (i < NN) row_start[i] = tmp[tid] - v;
    if (tid == 1023) partials[blockIdx.x] = tmp[tid];
}

__global__ void k_scan2(const int* __restrict__ partials, int* __restrict__ p_off, int nb) {
    __shared__ int tmp[128];
    int tid = threadIdx.x;
    int v = (tid < nb) ? partials[tid] : 0;
    tmp[tid] = v;
    __syncthreads();
    for (int off = 1; off < 128; off <<= 1) {
        int t = (tid >= off) ? tmp[tid - off] : 0;
        __syncthreads();
        tmp[tid] += t;
        __syncthreads();
    }
    if (tid < nb) p_off[tid] = tmp[tid] - v;
}

__global__ void k_scan3(int* __restrict__ row_start, const int* __restrict__ p_off) {
    int tid = threadIdx.x;
    int i = blockIdx.x * 1024 + tid;
    if (i < NN) row_start[i] += p_off[blockIdx.x];
    if (i == 0) row_start[NN] = EE;
}

// atomic-free scatter: pos = row_start[d] + rank[e]
__global__ void k_scatter(const int* __restrict__ ei, const float* __restrict__ ew,
                          const float* __restrict__ dinv, const int* __restrict__ row_start,
                          const int* __restrict__ rank, float2* __restrict__ es) {
    int e = blockIdx.x * 256 + threadIdx.x;
    if (e < EE) {
        int s = ei[e];
        int d = ei[EE + e];
        int pos = row_start[d] + rank[e];
        es[pos] = make_float2(__int_as_float(s), dinv[s] * ew[e] * dinv[d]);
    }
}

// ---------- dense layers ----------

// z = lrelu(x @ W_first + b_first), fp16 out   x:[N,128] W:[128,48]
__global__ __launch_bounds__(256) void k_mm1(const float* __restrict__ x, const float* __restrict__ W,
                                             const float* __restrict__ b, half4* __restrict__ z) {
    __shared__ float4 sW4[F_IN * HID / 4];   // 24 KB
    __shared__ float sB[HID];
    int tid = threadIdx.x;
    const float4* W4 = (const float4*)W;
    for (int i = tid; i < F_IN * HID / 4; i += 256) sW4[i] = W4[i];
    if (tid < HID) sB[tid] = b[tid];
    __syncthreads();
    int r = blockIdx.x * 256 + tid;
    if (r >= NN) return;
    float4 acc[12];
#pragma unroll
    for (int j = 0; j < 12; j++) {
        acc[j].x = sB[4 * j]; acc[j].y = sB[4 * j + 1];
        acc[j].z = sB[4 * j + 2]; acc[j].w = sB[4 * j + 3];
    }
    const float4* xr = (const float4*)(x + (size_t)r * F_IN);
    for (int k4 = 0; k4 < F_IN / 4; k4++) {
        float4 xv = xr[k4];
        float xs[4] = {xv.x, xv.y, xv.z, xv.w};
#pragma unroll
        for (int q = 0; q < 4; q++) {
            int k = k4 * 4 + q;
#pragma unroll
            for (int j = 0; j < 12; j++) fma4(acc[j], xs[q], sW4[k * 12 + j]);
        }
    }
    half4* zr = z + (size_t)r * 12;
#pragma unroll
    for (int j = 0; j < 12; j++) {
        float4 v = acc[j];
        v.x = v.x >= 0.f ? v.x : SLOPE * v.x;
        v.y = v.y >= 0.f ? v.y : SLOPE * v.y;
        v.z = v.z >= 0.f ? v.z : SLOPE * v.z;
        v.w = v.w >= 0.f ? v.w : SLOPE * v.w;
        half4 o;
        o.x = (_Float16)v.x; o.y = (_Float16)v.y;
        o.z = (_Float16)v.z; o.w = (_Float16)v.w;
        zr[j] = o;
    }
}

// stats for z0 (fp16 input): wave-per-row, lane<48 = column
__global__ __launch_bounds__(256) void k_stats(const _Float16* __restrict__ z, float* __restrict__ stats) {
    __shared__ float sS[HID], sQ[HID];
    int tid = threadIdx.x;
    int wid = tid >> 6, lane = tid & 63;
    if (tid < HID) { sS[tid] = 0.f; sQ[tid] = 0.f; }
    __syncthreads();
    if (lane < HID) {
        float s = 0.f, q = 0.f;
        for (int r = blockIdx.x * 4 + wid; r < NN; r += gridDim.x * 4) {
            float v = (float)z[(size_t)r * HID + lane];
            s += v; q += v * v;
        }
        atomicAdd(&sS[lane], s);
        atomicAdd(&sQ[lane], q);
    }
    __syncthreads();
    if (tid < HID) {
        atomicAdd(&stats[tid], sS[tid]);
        atomicAdd(&stats[HID + tid], sQ[tid]);
    }
}

// t = z @ Wp + rc  (BN folded into Wp/rc); fp16 in, fp16 out
__global__ __launch_bounds__(256) void k_mm48(const half4* __restrict__ z, const float* __restrict__ Wp,
                                              const float* __restrict__ rc, half4* __restrict__ t) {
    __shared__ float4 sW4[HID * HID / 4];    // 9.2 KB
    __shared__ float sR[HID];
    int tid = threadIdx.x;
    const float4* W4 = (const float4*)Wp;
    for (int i = tid; i < HID * HID / 4; i += 256) sW4[i] = W4[i];
    if (tid < HID) sR[tid] = rc[tid];
    __syncthreads();
    int r = blockIdx.x * 256 + tid;
    if (r >= NN) return;
    float4 acc[12];
#pragma unroll
    for (int j = 0; j < 12; j++) {
        acc[j].x = sR[4 * j]; acc[j].y = sR[4 * j + 1];
        acc[j].z = sR[4 * j + 2]; acc[j].w = sR[4 * j + 3];
    }
    const half4* hr = z + (size_t)r * 12;
#pragma unroll 4
    for (int k4 = 0; k4 < 12; k4++) {
        half4 hv = hr[k4];
        float xs[4] = {(float)hv.x, (float)hv.y, (float)hv.z, (float)hv.w};
#pragma unroll
        for (int q = 0; q < 4; q++) {
            int k = k4 * 4 + q;
#pragma unroll
            for (int j = 0; j < 12; j++) fma4(acc[j], xs[q], sW4[k * 12 + j]);
        }
    }
    half4* tr = t + (size_t)r * 12;
#pragma unroll
    for (int j = 0; j < 12; j++) {
        half4 o;
        o.x = (_Float16)acc[j].x; o.y = (_Float16)acc[j].y;
        o.z = (_Float16)acc[j].z; o.w = (_Float16)acc[j].w;
        tr[j] = o;
    }
}

// aggregation + fused BN stats.
// one wave per dst row (grid-stride); 8 groups of 8 lanes, each group one edge;
// 6 active lanes/group gather half8 (16B) = full 96B row; depth-1 data prefetch.
__global__ __launch_bounds__(256) void k_agg(const half8* __restrict__ hw, const int* __restrict__ row_start,
                                             const float2* __restrict__ es, const float* __restrict__ dinv,
                                             const float* __restrict__ bias, half8* __restrict__ z,
                                             float* __restrict__ stats) {
    __shared__ float bS[96];
    int tid = threadIdx.x;
    for (int i = tid; i < 96; i += 256) bS[i] = 0.f;
    __syncthreads();

    int wid = tid >> 6, lane = tid & 63;
    int g = lane >> 3, sub = lane & 7;
    bool act = sub < 6;
    int subidx = act ? sub : 0;
    int wgid = blockIdx.x * 4 + wid;
    const int nwaves = AGG_BLOCKS * 4;
    bool writer = (g == 0) && act;

    float bl[8];
#pragma unroll
    for (int c = 0; c < 8; c++) bl[c] = bias[subidx * 8 + c];

    float s8[8], q8[8];
#pragma unroll
    for (int c = 0; c < 8; c++) { s8[c] = 0.f; q8[c] = 0.f; }

    for (int n = wgid; n < NN; n += nwaves) {
        float acc[8];
#pragma unroll
        for (int c = 0; c < 8; c++) acc[c] = 0.f;
        if (writer) {
            float di = dinv[n];
            float w = di * di;
            half8 v = hw[(size_t)n * 6 + sub];
#pragma unroll
            for (int c = 0; c < 8; c++) acc[c] = w * (float)v[c];
        }
        int e0 = row_start[n], e1 = row_start[n + 1];
        int e = e0 + g;
        float2 meta = (e < e1) ? es[e] : make_float2(0.f, 0.f);
        half8 row = hw[(size_t)__float_as_int(meta.x) * 6 + subidx];
        int nit = (e1 - e0 + 7) >> 3;
        for (int i = 0; i < nit; i++) {
            float w = meta.y;
            half8 cur = row;
            e += 8;
            meta = (e < e1) ? es[e] : make_float2(0.f, 0.f);
            row = hw[(size_t)__float_as_int(meta.x) * 6 + subidx];   // prefetch next
#pragma unroll
            for (int c = 0; c < 8; c++) acc[c] += w * (float)cur[c];
        }
        // reduce across the 8 groups
#pragma unroll
        for (int off = 8; off <= 32; off <<= 1) {
#pragma unroll
            for (int c = 0; c < 8; c++) acc[c] += __shfl_xor(acc[c], off);
        }
        if (writer) {
            half8 o;
#pragma unroll
            for (int c = 0; c < 8; c++) {
                float v = acc[c] + bl[c];
                v = v >= 0.f ? v : SLOPE * v;
                s8[c] += v; q8[c] += v * v;
                o[c] = (_Float16)v;
            }
            z[(size_t)n * 6 + sub] = o;
        }
    }
    // block-level stats combine
    if (writer) {
#pragma unroll
        for (int c = 0; c < 8; c++) {
            atomicAdd(&bS[sub * 8 + c], s8[c]);
            atomicAdd(&bS[48 + sub * 8 + c], q8[c]);
        }
    }
    __syncthreads();
    if (tid < 96) {
        int j = (tid + blockIdx.x) % 96;   // stagger to spread atomic contention
        atomicAdd(&stats[j], bS[j]);
    }
}

// ---------- batch norm folding ----------

// compute a,c from stats; fold into W (48x48): Wp[k][j]=a[k]W[k][j], rc[j]=sum_k c[k]W[k][j]
__global__ __launch_bounds__(256) void k_bn_fold(const float* __restrict__ stats, const float* __restrict__ g,
                                                 const float* __restrict__ b, const float* __restrict__ W,
                                                 float* __restrict__ ac, float* __restrict__ Wp,
                                                 float* __restrict__ rc) {
    __shared__ float sA[HID], sC[HID];
    int tid = threadIdx.x;
    if (tid < HID) {
        float mean = stats[tid] * (1.0f / (float)NN);
        float var = stats[HID + tid] * (1.0f / (float)NN) - mean * mean;
        float a = g[tid] * rsqrtf(var + EPSV);
        float c = b[tid] - mean * a;
        sA[tid] = a; sC[tid] = c;
        ac[tid] = a; ac[HID + tid] = c;
    }
    __syncthreads();
    for (int i = tid; i < HID * HID; i += 256) Wp[i] = sA[i / HID] * W[i];
    if (tid < HID) {
        float acc = 0.f;
        for (int k = 0; k < HID; k++) acc += sC[k] * W[k * HID + tid];
        rc[tid] = acc;
    }
}

// fold BN1/BN2 (from ac) and BN3 (from stats2) into W_out: Wp[144][40], bc[40]
__global__ __launch_bounds__(256) void k_fold_final(const float* __restrict__ ac0, const float* __restrict__ ac1,
                                                    const float* __restrict__ stats2, const float* __restrict__ g3,
                                                    const float* __restrict__ b3, const float* __restrict__ W,
                                                    const float* __restrict__ b, float* __restrict__ Wp,
                                                    float* __restrict__ bc) {
    __shared__ float sA[3 * HID], sC[3 * HID];
    int tid = threadIdx.x;
    if (tid < 96) {
        const float* a = (tid < HID) ? ac0 : ac1;
        int j = tid % HID;
        sA[tid] = a[j]; sC[tid] = a[HID + j];
    } else if (tid < 144) {
        int j = tid - 96;
        float mean = stats2[j] * (1.0f / (float)NN);
        float var = stats2[HID + j] * (1.0f / (float)NN) - mean * mean;
        float a = g3[j] * rsqrtf(var + EPSV);
        sA[tid] = a; sC[tid] = b3[j] - mean * a;
    }
    __syncthreads();
    for (int i = tid; i < 3 * HID * NCLS; i += 256) Wp[i] = sA[i / NCLS] * W[i];
    if (tid < NCLS) {
        float acc = b[tid];
        for (int k = 0; k < 3 * HID; k++) acc += sC[k] * W[k * NCLS + tid];
        bc[tid] = acc;
    }
}

// ---------- output layer (fp16 z inputs; BN folded into Wp/bc) ----------

__global__ __launch_bounds__(256) void k_final(const half4* __restrict__ z0, const half4* __restrict__ z1,
                                               const half4* __restrict__ z2, const float* __restrict__ Wp,
                                               const float* __restrict__ bc, float* __restrict__ out) {
    __shared__ float4 sW4[3 * HID * NCLS / 4];   // 23 KB
    __shared__ float sB[NCLS];
    int tid = threadIdx.x;
    const float4* W4 = (const float4*)Wp;
    for (int i = tid; i < 3 * HID * NCLS / 4; i += 256) sW4[i] = W4[i];
    if (tid < NCLS) sB[tid] = bc[tid];
    __syncthreads();
    int r = blockIdx.x * 256 + tid;
    if (r >= NN) return;
    float4 acc[10];
#pragma unroll
    for (int j = 0; j < 10; j++) {
        acc[j].x = sB[4 * j]; acc[j].y = sB[4 * j + 1];
        acc[j].z = sB[4 * j + 2]; acc[j].w = sB[4 * j + 3];
    }
    const half4* zs[3] = {z0, z1, z2};
#pragma unroll
    for (int part = 0; part < 3; part++) {
        const half4* hr = zs[part] + (size_t)r * 12;
        for (int k4 = 0; k4 < 12; k4++) {
            half4 hv = hr[k4];
            float xs[4] = {(float)hv.x, (float)hv.y, (float)hv.z, (float)hv.w};
#pragma unroll
            for (int q = 0; q < 4; q++) {
                int k = part * HID + k4 * 4 + q;
#pragma unroll
                for (int j = 0; j < 10; j++) fma4(acc[j], xs[q], sW4[k * 10 + j]);
            }
        }
    }
    float m = -1e30f;
#pragma unroll
    for (int j = 0; j < 10; j++)
        m = fmaxf(m, fmaxf(fmaxf(acc[j].x, acc[j].y), fmaxf(acc[j].z, acc[j].w)));
    float s = 0.f;
#pragma unroll
    for (int j = 0; j < 10; j++)
        s += __expf(acc[j].x - m) + __expf(acc[j].y - m) + __expf(acc[j].z - m) + __expf(acc[j].w - m);
    float l = m + __logf(s);
    float4* orow = (float4*)(out + (size_t)r * NCLS);
#pragma unroll
    for (int j = 0; j < 10; j++) {
        float4 v = acc[j];
        v.x -= l; v.y -= l; v.z -= l; v.w -= l;
        orow[j] = v;
    }
}

// ---------- launch ----------

extern "C" void kernel_launch(void* const* d_in, const int* in_sizes, int n_in,
                              void* d_out, int out_size, void* d_ws, size_t ws_size,
                              hipStream_t stream) {
    const float* x       = (const float*)d_in[0];
    const int*   ei      = (const int*)d_in[1];
    const float* ew      = (const float*)d_in[2];
    const float* W_first = (const float*)d_in[3];
    const float* b_first = (const float*)d_in[4];
    const float* bn1_g   = (const float*)d_in[5];
    const float* bn1_b   = (const float*)d_in[6];
    const float* Wc1     = (const float*)d_in[7];
    const float* bc1     = (const float*)d_in[8];
    const float* bn2_g   = (const float*)d_in[9];
    const float* bn2_b   = (const float*)d_in[10];
    const float* Wc2     = (const float*)d_in[11];
    const float* bc2     = (const float*)d_in[12];
    const float* bn3_g   = (const float*)d_in[13];
    const float* bn3_b   = (const float*)d_in[14];
    const float* W_out   = (const float*)d_in[15];
    const float* b_out   = (const float*)d_in[16];
    float* out = (float*)d_out;

    // workspace layout — all region sizes multiples of 16B; packed+stats adjacent for one memset
    char* wsb = (char*)d_ws;
    _Float16* z0h = (_Float16*)wsb;                         // N*48 fp16  (9.6 MB)
    _Float16* z1h = z0h + (size_t)NN * HID;
    _Float16* z2h = z1h + (size_t)NN * HID;
    _Float16* tbh = z2h + (size_t)NN * HID;                 // gather table fp16
    unsigned long long* packed = (unsigned long long*)(tbh + (size_t)NN * HID);  // N u64
    float* stats  = (float*)(packed + NN);                  // 3*96 (zeroed with packed)
    float* dinv   = stats + 288;                            // N
    int*   rank   = (int*)(dinv + NN);                      // E
    int*   row_st = rank + EE;                              // N+4
    float2* es    = (float2*)(row_st + NN + 4);             // E float2
    float* ac     = (float*)(es + EE);                      // 2*96 (BN1, BN2 a/c)
    float* Wp1    = ac + 192;                               // 2304
    float* rc1    = Wp1 + HID * HID;                        // 48
    float* Wp2    = rc1 + HID;                              // 2304
    float* rc2    = Wp2 + HID * HID;                        // 48
    float* WpO    = rc2 + HID;                              // 5760
    float* bcO    = WpO + 3 * HID * NCLS;                   // 40 (+pad)
    int*   partials = (int*)(bcO + 40 + 8);                 // 128
    int*   p_off  = partials + 128;                         // 128

    const int nb_scan = (NN + 1023) / 1024;
    const int blkN = (NN + 255) / 256;
    const int blkE = (EE + 255) / 256;

    // one memset: packed (800 KB) + stats (1152 B), contiguous
    hipMemsetAsync(packed, 0, sizeof(unsigned long long) * NN + sizeof(float) * 288, stream);

    // CSR build
    k_edge_deg<<<blkE, 256, 0, stream>>>(ei, ew, packed, rank);
    k_scan1<<<nb_scan, 1024, 0, stream>>>(packed, row_st, partials, dinv);
    k_scan2<<<1, 128, 0, stream>>>(partials, p_off, nb_scan);
    k_scan3<<<nb_scan, 1024, 0, stream>>>(row_st, p_off);
    k_scatter<<<blkE, 256, 0, stream>>>(ei, ew, dinv, row_st, rank, es);

    // layer 1
    k_mm1<<<blkN, 256, 0, stream>>>(x, W_first, b_first, (half4*)z0h);
    k_stats<<<256, 256, 0, stream>>>(z0h, stats);
    k_bn_fold<<<1, 256, 0, stream>>>(stats, bn1_g, bn1_b, Wc1, ac, Wp1, rc1);

    // conv 1 (agg fuses BN2 stats)
    k_mm48<<<blkN, 256, 0, stream>>>((const half4*)z0h, Wp1, rc1, (half4*)tbh);
    k_agg<<<AGG_BLOCKS, 256, 0, stream>>>((const half8*)tbh, row_st, es, dinv, bc1, (half8*)z1h, stats + 96);
    k_bn_fold<<<1, 256, 0, stream>>>(stats + 96, bn2_g, bn2_b, Wc2, ac + 96, Wp2, rc2);

    // conv 2 (agg fuses BN3 stats)
    k_mm48<<<blkN, 256, 0, stream>>>((const half4*)z1h, Wp2, rc2, (half4*)tbh);
    k_agg<<<AGG_BLOCKS, 256, 0, stream>>>((const half8*)tbh, row_st, es, dinv, bc2, (half8*)z2h, stats + 192);

    // fold BN1/2/3 into output weights; final layer + log_softmax
    k_fold_final<<<1, 256, 0, stream>>>(ac, ac + 96, stats + 192, bn3_g, bn3_b, W_out, b_out, WpO, bcO);
    k_final<<<blkN, 256, 0, stream>>>((const half4*)z0h, (const half4*)z1h, (const half4*)z2h, WpO, bcO, out);
}

// Round 5
// 552.344 us; speedup vs baseline: 1.0995x; 1.0995x over previous
//
#include <hip/hip_runtime.h>
#include <cstddef>

#define NN 100000
#define EE 1600000
#define F_IN 128
#define HID 48
#define NCLS 40
#define EPSV 1e-5f
#define SLOPE 0.01f
#define FIXP 16777216.0f   // 2^24 fixed-point scale for edge weights

typedef _Float16 half4 __attribute__((ext_vector_type(4)));

__device__ inline void fma4(float4& a, float s, const float4 w) {
    a.x += s * w.x; a.y += s * w.y; a.z += s * w.z; a.w += s * w.w;
}

// ---------- edge preprocessing ----------

// ONE u64 atomic per edge: high32 = count, low32 = fixed-point weight sum.
// Returned old count = this edge's rank within its destination row.
__global__ void k_edge_deg(const int* __restrict__ ei, const float* __restrict__ ew,
                           unsigned long long* __restrict__ packed, int* __restrict__ rank) {
    int e = blockIdx.x * 256 + threadIdx.x;
    if (e < EE) {
        int d = ei[EE + e];
        unsigned long long add = (1ULL << 32) | (unsigned long long)__float2uint_rn(ew[e] * FIXP);
        unsigned long long old = atomicAdd(&packed[d], add);
        rank[e] = (int)(old >> 32);
    }
}

// shfl-based block scan (256 threads) + dinv computation
__global__ __launch_bounds__(256) void k_scan1(const unsigned long long* __restrict__ packed,
                                               int* __restrict__ row_start, int* __restrict__ partials,
                                               float* __restrict__ dinv) {
    int tid = threadIdx.x;
    int i = blockIdx.x * 256 + tid;
    unsigned long long p = (i < NN) ? packed[i] : 0ULL;
    int v = (int)(p >> 32);
    if (i < NN) {
        float wdeg = (float)(unsigned int)(p & 0xffffffffULL) * (1.0f / FIXP);
        dinv[i] = rsqrtf(wdeg + 1.0f);   // +1 = self-loop weight; always > 0
    }
    int lane = tid & 63, w = tid >> 6;
    int incl = v;
#pragma unroll
    for (int off = 1; off < 64; off <<= 1) {
        int t = __shfl_up(incl, off);
        if (lane >= off) incl += t;
    }
    __shared__ int wsum[4];
    if (lane == 63) wsum[w] = incl;
    __syncthreads();
    int base = 0;
#pragma unroll
    for (int j = 0; j < 3; j++) base += (j < w) ? wsum[j] : 0;
    if (i < NN) row_start[i] = base + incl - v;        // block-local exclusive
    if (tid == 255) partials[blockIdx.x] = base + incl; // block total
}

__global__ __launch_bounds__(512) void k_scan2(const int* __restrict__ partials, int* __restrict__ p_off, int nb) {
    int tid = threadIdx.x;
    int v = (tid < nb) ? partials[tid] : 0;
    int lane = tid & 63, w = tid >> 6;
    int incl = v;
#pragma unroll
    for (int off = 1; off < 64; off <<= 1) {
        int t = __shfl_up(incl, off);
        if (lane >= off) incl += t;
    }
    __shared__ int wsum[8];
    if (lane == 63) wsum[w] = incl;
    __syncthreads();
    int base = 0;
#pragma unroll
    for (int j = 0; j < 7; j++) base += (j < w) ? wsum[j] : 0;
    if (tid < nb) p_off[tid] = base + incl - v;        // exclusive
}

__global__ __launch_bounds__(256) void k_scan3(int* __restrict__ row_start, const int* __restrict__ p_off) {
    int tid = threadIdx.x;
    int i = blockIdx.x * 256 + tid;
    if (i < NN) row_start[i] += p_off[blockIdx.x];
    if (i == 0) row_start[NN] = EE;
}

// atomic-free scatter: pos = row_start[d] + rank[e]
__global__ void k_scatter(const int* __restrict__ ei, const float* __restrict__ ew,
                          const float* __restrict__ dinv, const int* __restrict__ row_start,
                          const int* __restrict__ rank, float2* __restrict__ es) {
    int e = blockIdx.x * 256 + threadIdx.x;
    if (e < EE) {
        int s = ei[e];
        int d = ei[EE + e];
        int pos = row_start[d] + rank[e];
        es[pos] = make_float2(__int_as_float(s), dinv[s] * ew[e] * dinv[d]);
    }
}

// ---------- dense layers ----------

// z = lrelu(x @ W_first + b_first), fp16 out   x:[N,128] W:[128,48]
__global__ __launch_bounds__(256) void k_mm1(const float* __restrict__ x, const float* __restrict__ W,
                                             const float* __restrict__ b, half4* __restrict__ z) {
    __shared__ float4 sW4[F_IN * HID / 4];   // 24 KB
    __shared__ float sB[HID];
    int tid = threadIdx.x;
    const float4* W4 = (const float4*)W;
    for (int i = tid; i < F_IN * HID / 4; i += 256) sW4[i] = W4[i];
    if (tid < HID) sB[tid] = b[tid];
    __syncthreads();
    int r = blockIdx.x * 256 + tid;
    if (r >= NN) return;
    float4 acc[12];
#pragma unroll
    for (int j = 0; j < 12; j++) {
        acc[j].x = sB[4 * j]; acc[j].y = sB[4 * j + 1];
        acc[j].z = sB[4 * j + 2]; acc[j].w = sB[4 * j + 3];
    }
    const float4* xr = (const float4*)(x + (size_t)r * F_IN);
    for (int k4 = 0; k4 < F_IN / 4; k4++) {
        float4 xv = xr[k4];
        float xs[4] = {xv.x, xv.y, xv.z, xv.w};
#pragma unroll
        for (int q = 0; q < 4; q++) {
            int k = k4 * 4 + q;
#pragma unroll
            for (int j = 0; j < 12; j++) fma4(acc[j], xs[q], sW4[k * 12 + j]);
        }
    }
    half4* zr = z + (size_t)r * 12;
#pragma unroll
    for (int j = 0; j < 12; j++) {
        float4 v = acc[j];
        v.x = v.x >= 0.f ? v.x : SLOPE * v.x;
        v.y = v.y >= 0.f ? v.y : SLOPE * v.y;
        v.z = v.z >= 0.f ? v.z : SLOPE * v.z;
        v.w = v.w >= 0.f ? v.w : SLOPE * v.w;
        half4 o;
        o.x = (_Float16)v.x; o.y = (_Float16)v.y;
        o.z = (_Float16)v.z; o.w = (_Float16)v.w;
        zr[j] = o;
    }
}

// BN stats (fp16 input): wave-per-row, lane<48 = column
__global__ __launch_bounds__(256) void k_stats(const _Float16* __restrict__ z, float* __restrict__ stats) {
    __shared__ float sS[HID], sQ[HID];
    int tid = threadIdx.x;
    int wid = tid >> 6, lane = tid & 63;
    if (tid < HID) { sS[tid] = 0.f; sQ[tid] = 0.f; }
    __syncthreads();
    if (lane < HID) {
        float s = 0.f, q = 0.f;
        for (int r = blockIdx.x * 4 + wid; r < NN; r += gridDim.x * 4) {
            float v = (float)z[(size_t)r * HID + lane];
            s += v; q += v * v;
        }
        atomicAdd(&sS[lane], s);
        atomicAdd(&sQ[lane], q);
    }
    __syncthreads();
    if (tid < HID) {
        atomicAdd(&stats[tid], sS[tid]);
        atomicAdd(&stats[HID + tid], sQ[tid]);
    }
}

// t = z @ Wp + rc  (BN folded into Wp/rc); fp16 in, fp16 out
__global__ __launch_bounds__(256) void k_mm48(const half4* __restrict__ z, const float* __restrict__ Wp,
                                              const float* __restrict__ rc, half4* __restrict__ t) {
    __shared__ float4 sW4[HID * HID / 4];    // 9.2 KB
    __shared__ float sR[HID];
    int tid = threadIdx.x;
    const float4* W4 = (const float4*)Wp;
    for (int i = tid; i < HID * HID / 4; i += 256) sW4[i] = W4[i];
    if (tid < HID) sR[tid] = rc[tid];
    __syncthreads();
    int r = blockIdx.x * 256 + tid;
    if (r >= NN) return;
    float4 acc[12];
#pragma unroll
    for (int j = 0; j < 12; j++) {
        acc[j].x = sR[4 * j]; acc[j].y = sR[4 * j + 1];
        acc[j].z = sR[4 * j + 2]; acc[j].w = sR[4 * j + 3];
    }
    const half4* hr = z + (size_t)r * 12;
#pragma unroll 4
    for (int k4 = 0; k4 < 12; k4++) {
        half4 hv = hr[k4];
        float xs[4] = {(float)hv.x, (float)hv.y, (float)hv.z, (float)hv.w};
#pragma unroll
        for (int q = 0; q < 4; q++) {
            int k = k4 * 4 + q;
#pragma unroll
            for (int j = 0; j < 12; j++) fma4(acc[j], xs[q], sW4[k * 12 + j]);
        }
    }
    half4* tr = t + (size_t)r * 12;
#pragma unroll
    for (int j = 0; j < 12; j++) {
        half4 o;
        o.x = (_Float16)acc[j].x; o.y = (_Float16)acc[j].y;
        o.z = (_Float16)acc[j].z; o.w = (_Float16)acc[j].w;
        tr[j] = o;
    }
}

// aggregation: z[n] = lrelu( sum_in-edges hw[src]*norm + hw[n]*dinv[n]^2 + bias )
// one wave per dst row; 4 groups of 16 lanes each handle one edge; 12 active lanes gather half4.
// block=256 -> 4 rows/block, 25000 blocks: max oversubscription for latency hiding.
__global__ __launch_bounds__(256) void k_agg(const half4* __restrict__ hw, const int* __restrict__ row_start,
                                             const float2* __restrict__ es, const float* __restrict__ dinv,
                                             const float* __restrict__ bias, half4* __restrict__ z) {
    int n = blockIdx.x * 4 + (threadIdx.x >> 6);
    int lane = threadIdx.x & 63;
    int g = lane >> 4, sub = lane & 15;
    bool act = sub < 12;
    float4 acc = make_float4(0.f, 0.f, 0.f, 0.f);
    if (g == 0 && act) {
        float di = dinv[n];
        float w = di * di;
        half4 v = hw[(size_t)n * 12 + sub];
        acc.x = w * (float)v.x; acc.y = w * (float)v.y;
        acc.z = w * (float)v.z; acc.w = w * (float)v.w;
    }
    int e0 = row_start[n], e1 = row_start[n + 1];
    int eg = e0 + g;
    float2 meta = (eg < e1) ? es[eg] : make_float2(0.f, 0.f);
    for (int e = e0; e < e1; e += 4) {
        float2 cur = meta;
        int egn = e + 4 + g;
        meta = (egn < e1) ? es[egn] : make_float2(0.f, 0.f);
        if (e + g < e1 && act) {
            int s = __float_as_int(cur.x);
            float w = cur.y;
            half4 v = hw[(size_t)s * 12 + sub];
            acc.x += w * (float)v.x; acc.y += w * (float)v.y;
            acc.z += w * (float)v.z; acc.w += w * (float)v.w;
        }
    }
#pragma unroll
    for (int off = 16; off <= 32; off <<= 1) {
        acc.x += __shfl_xor(acc.x, off);
        acc.y += __shfl_xor(acc.y, off);
        acc.z += __shfl_xor(acc.z, off);
        acc.w += __shfl_xor(acc.w, off);
    }
    if (g == 0 && act) {
        const float4* b4 = (const float4*)bias;
        float4 bv = b4[sub];
        float4 v;
        v.x = acc.x + bv.x; v.y = acc.y + bv.y; v.z = acc.z + bv.z; v.w = acc.w + bv.w;
        v.x = v.x >= 0.f ? v.x : SLOPE * v.x;
        v.y = v.y >= 0.f ? v.y : SLOPE * v.y;
        v.z = v.z >= 0.f ? v.z : SLOPE * v.z;
        v.w = v.w >= 0.f ? v.w : SLOPE * v.w;
        half4 o;
        o.x = (_Float16)v.x; o.y = (_Float16)v.y;
        o.z = (_Float16)v.z; o.w = (_Float16)v.w;
        z[(size_t)n * 12 + sub] = o;
    }
}

// ---------- batch norm folding ----------

// compute a,c from stats; fold into W (48x48): Wp[k][j]=a[k]W[k][j], rc[j]=sum_k c[k]W[k][j]
__global__ __launch_bounds__(256) void k_bn_fold(const float* __restrict__ stats, const float* __restrict__ g,
                                                 const float* __restrict__ b, const float* __restrict__ W,
                                                 float* __restrict__ ac, float* __restrict__ Wp,
                                                 float* __restrict__ rc) {
    __shared__ float sA[HID], sC[HID];
    int tid = threadIdx.x;
    if (tid < HID) {
        float mean = stats[tid] * (1.0f / (float)NN);
        float var = stats[HID + tid] * (1.0f / (float)NN) - mean * mean;
        float a = g[tid] * rsqrtf(var + EPSV);
        float c = b[tid] - mean * a;
        sA[tid] = a; sC[tid] = c;
        ac[tid] = a; ac[HID + tid] = c;
    }
    __syncthreads();
    for (int i = tid; i < HID * HID; i += 256) Wp[i] = sA[i / HID] * W[i];
    if (tid < HID) {
        float acc = 0.f;
        for (int k = 0; k < HID; k++) acc += sC[k] * W[k * HID + tid];
        rc[tid] = acc;
    }
}

// fold BN1/BN2 (from ac) and BN3 (from stats2) into W_out: Wp[144][40], bc[40]
__global__ __launch_bounds__(256) void k_fold_final(const float* __restrict__ ac0, const float* __restrict__ ac1,
                                                    const float* __restrict__ stats2, const float* __restrict__ g3,
                                                    const float* __restrict__ b3, const float* __restrict__ W,
                                                    const float* __restrict__ b, float* __restrict__ Wp,
                                                    float* __restrict__ bc) {
    __shared__ float sA[3 * HID], sC[3 * HID];
    int tid = threadIdx.x;
    if (tid < 96) {
        const float* a = (tid < HID) ? ac0 : ac1;
        int j = tid % HID;
        sA[tid] = a[j]; sC[tid] = a[HID + j];
    } else if (tid < 144) {
        int j = tid - 96;
        float mean = stats2[j] * (1.0f / (float)NN);
        float var = stats2[HID + j] * (1.0f / (float)NN) - mean * mean;
        float a = g3[j] * rsqrtf(var + EPSV);
        sA[tid] = a; sC[tid] = b3[j] - mean * a;
    }
    __syncthreads();
    for (int i = tid; i < 3 * HID * NCLS; i += 256) Wp[i] = sA[i / NCLS] * W[i];
    if (tid < NCLS) {
        float acc = b[tid];
        for (int k = 0; k < 3 * HID; k++) acc += sC[k] * W[k * NCLS + tid];
        bc[tid] = acc;
    }
}

// ---------- output layer (fp16 z inputs; BN folded into Wp/bc) ----------

__global__ __launch_bounds__(256) void k_final(const half4* __restrict__ z0, const half4* __restrict__ z1,
                                               const half4* __restrict__ z2, const float* __restrict__ Wp,
                                               const float* __restrict__ bc, float* __restrict__ out) {
    __shared__ float4 sW4[3 * HID * NCLS / 4];   // 23 KB
    __shared__ float sB[NCLS];
    int tid = threadIdx.x;
    const float4* W4 = (const float4*)Wp;
    for (int i = tid; i < 3 * HID * NCLS / 4; i += 256) sW4[i] = W4[i];
    if (tid < NCLS) sB[tid] = bc[tid];
    __syncthreads();
    int r = blockIdx.x * 256 + tid;
    if (r >= NN) return;
    float4 acc[10];
#pragma unroll
    for (int j = 0; j < 10; j++) {
        acc[j].x = sB[4 * j]; acc[j].y = sB[4 * j + 1];
        acc[j].z = sB[4 * j + 2]; acc[j].w = sB[4 * j + 3];
    }
    const half4* zs[3] = {z0, z1, z2};
#pragma unroll
    for (int part = 0; part < 3; part++) {
        const half4* hr = zs[part] + (size_t)r * 12;
        for (int k4 = 0; k4 < 12; k4++) {
            half4 hv = hr[k4];
            float xs[4] = {(float)hv.x, (float)hv.y, (float)hv.z, (float)hv.w};
#pragma unroll
            for (int q = 0; q < 4; q++) {
                int k = part * HID + k4 * 4 + q;
#pragma unroll
                for (int j = 0; j < 10; j++) fma4(acc[j], xs[q], sW4[k * 10 + j]);
            }
        }
    }
    float m = -1e30f;
#pragma unroll
    for (int j = 0; j < 10; j++)
        m = fmaxf(m, fmaxf(fmaxf(acc[j].x, acc[j].y), fmaxf(acc[j].z, acc[j].w)));
    float s = 0.f;
#pragma unroll
    for (int j = 0; j < 10; j++)
        s += __expf(acc[j].x - m) + __expf(acc[j].y - m) + __expf(acc[j].z - m) + __expf(acc[j].w - m);
    float l = m + __logf(s);
    float4* orow = (float4*)(out + (size_t)r * NCLS);
#pragma unroll
    for (int j = 0; j < 10; j++) {
        float4 v = acc[j];
        v.x -= l; v.y -= l; v.z -= l; v.w -= l;
        orow[j] = v;
    }
}

// ---------- launch ----------

extern "C" void kernel_launch(void* const* d_in, const int* in_sizes, int n_in,
                              void* d_out, int out_size, void* d_ws, size_t ws_size,
                              hipStream_t stream) {
    const float* x       = (const float*)d_in[0];
    const int*   ei      = (const int*)d_in[1];
    const float* ew      = (const float*)d_in[2];
    const float* W_first = (const float*)d_in[3];
    const float* b_first = (const float*)d_in[4];
    const float* bn1_g   = (const float*)d_in[5];
    const float* bn1_b   = (const float*)d_in[6];
    const float* Wc1     = (const float*)d_in[7];
    const float* bc1     = (const float*)d_in[8];
    const float* bn2_g   = (const float*)d_in[9];
    const float* bn2_b   = (const float*)d_in[10];
    const float* Wc2     = (const float*)d_in[11];
    const float* bc2     = (const float*)d_in[12];
    const float* bn3_g   = (const float*)d_in[13];
    const float* bn3_b   = (const float*)d_in[14];
    const float* W_out   = (const float*)d_in[15];
    const float* b_out   = (const float*)d_in[16];
    float* out = (float*)d_out;

    // workspace layout — packed+stats adjacent for one memset
    char* wsb = (char*)d_ws;
    _Float16* z0h = (_Float16*)wsb;                         // N*48 fp16  (9.6 MB)
    _Float16* z1h = z0h + (size_t)NN * HID;
    _Float16* z2h = z1h + (size_t)NN * HID;
    _Float16* tbh = z2h + (size_t)NN * HID;                 // gather table fp16
    unsigned long long* packed = (unsigned long long*)(tbh + (size_t)NN * HID);  // N u64
    float* stats  = (float*)(packed + NN);                  // 3*96 (zeroed with packed)
    float* dinv   = stats + 288;                            // N
    int*   rank   = (int*)(dinv + NN);                      // E
    int*   row_st = rank + EE;                              // N+4
    float2* es    = (float2*)(row_st + NN + 4);             // E float2
    float* ac     = (float*)(es + EE);                      // 2*96 (BN1, BN2 a/c)
    float* Wp1    = ac + 192;                               // 2304
    float* rc1    = Wp1 + HID * HID;                        // 48
    float* Wp2    = rc1 + HID;                              // 2304
    float* rc2    = Wp2 + HID * HID;                        // 48
    float* WpO    = rc2 + HID;                              // 5760
    float* bcO    = WpO + 3 * HID * NCLS;                   // 40 (+pad)
    int*   partials = (int*)(bcO + 40 + 8);                 // 512
    int*   p_off  = partials + 512;                         // 512

    const int blkN = (NN + 255) / 256;   // 391
    const int blkE = (EE + 255) / 256;

    hipMemsetAsync(packed, 0, sizeof(unsigned long long) * NN + sizeof(float) * 288, stream);

    // CSR build
    k_edge_deg<<<blkE, 256, 0, stream>>>(ei, ew, packed, rank);
    k_scan1<<<blkN, 256, 0, stream>>>(packed, row_st, partials, dinv);
    k_scan2<<<1, 512, 0, stream>>>(partials, p_off, blkN);
    k_scan3<<<blkN, 256, 0, stream>>>(row_st, p_off);
    k_scatter<<<blkE, 256, 0, stream>>>(ei, ew, dinv, row_st, rank, es);

    // layer 1
    k_mm1<<<blkN, 256, 0, stream>>>(x, W_first, b_first, (half4*)z0h);
    k_stats<<<256, 256, 0, stream>>>(z0h, stats);
    k_bn_fold<<<1, 256, 0, stream>>>(stats, bn1_g, bn1_b, Wc1, ac, Wp1, rc1);

    // conv 1
    k_mm48<<<blkN, 256, 0, stream>>>((const half4*)z0h, Wp1, rc1, (half4*)tbh);
    k_agg<<<NN / 4, 256, 0, stream>>>((const half4*)tbh, row_st, es, dinv, bc1, (half4*)z1h);
    k_stats<<<256, 256, 0, stream>>>(z1h, stats + 96);
    k_bn_fold<<<1, 256, 0, stream>>>(stats + 96, bn2_g, bn2_b, Wc2, ac + 96, Wp2, rc2);

    // conv 2
    k_mm48<<<blkN, 256, 0, stream>>>((const half4*)z1h, Wp2, rc2, (half4*)tbh);
    k_agg<<<NN / 4, 256, 0, stream>>>((const half4*)tbh, row_st, es, dinv, bc2, (half4*)z2h);
    k_stats<<<256, 256, 0, stream>>>(z2h, stats + 192);

    // fold BN1/2/3 into output weights; final layer + log_softmax
    k_fold_final<<<1, 256, 0, stream>>>(ac, ac + 96, stats + 192, bn3_g, bn3_b, W_out, b_out, WpO, bcO);
    k_final<<<blkN, 256, 0, stream>>>((const half4*)z0h, (const half4*)z1h, (const half4*)z2h, WpO, bcO, out);
}